// Round 5
// baseline (287.299 us; speedup 1.0000x reference)
//
#include <hip/hip_runtime.h>
#include <cstdint>

#define E_EXP 8
#define BATCH 8192
#define D0 480
#define D1 512
#define D2 512
#define D3 363
#define KP 512      // padded per-expert K
#define N3PAD 384

typedef _Float16 f16x8 __attribute__((ext_vector_type(8)));
typedef float f32x4 __attribute__((ext_vector_type(4)));
typedef unsigned short u16;
typedef u16 u16x8 __attribute__((ext_vector_type(8)));

__device__ __forceinline__ u16 f2h(float f) {
    _Float16 h = (_Float16)f;
    return __builtin_bit_cast(u16, h);
}

// async global->LDS, 16B per lane; LDS dest = wave-uniform base + lane*16
__device__ __forceinline__ void async16(const u16* g, u16* s) {
    __builtin_amdgcn_global_load_lds(
        reinterpret_cast<const __attribute__((address_space(1))) void*>(
            reinterpret_cast<uintptr_t>(g)),
        reinterpret_cast<__attribute__((address_space(3))) void*>(
            reinterpret_cast<uintptr_t>(s)),
        16, 0, 0);
}

// W[e][o][i] fp32 -> wf[e][o][0..511] fp16, zero-padded in o (to OUTP) and i (to 512)
__device__ __forceinline__ void pack_seg(const float* __restrict__ src,
                                         u16* __restrict__ dst,
                                         int OUT_src, int OUTP, int IN_src) {
    int total = E_EXP * OUTP * 128;  // dword4 chunks of the 512-wide dst
    int in4 = IN_src >> 2;
    for (int idx = blockIdx.x * blockDim.x + threadIdx.x; idx < total;
         idx += gridDim.x * blockDim.x) {
        int e = idx / (OUTP * 128);
        int r = idx - e * OUTP * 128;
        int o = r >> 7;
        int k4 = r & 127;
        ushort4 w;
        if (o < OUT_src && k4 < in4) {
            const float4 v = *reinterpret_cast<const float4*>(
                src + ((size_t)e * OUT_src + o) * IN_src + (k4 << 2));
            w.x = f2h(v.x); w.y = f2h(v.y); w.z = f2h(v.z); w.w = f2h(v.w);
        } else {
            w.x = 0; w.y = 0; w.z = 0; w.w = 0;
        }
        *reinterpret_cast<ushort4*>(dst + ((size_t)e * OUTP + o) * KP + (k4 << 2)) = w;
    }
}

__global__ void pack_all(const float* __restrict__ W1, const float* __restrict__ W2,
                         const float* __restrict__ W3, u16* __restrict__ wf1,
                         u16* __restrict__ wf2, u16* __restrict__ wf3) {
    pack_seg(W1, wf1, 512, 512, D0);
    pack_seg(W2, wf2, 512, 512, D1);
    pack_seg(W3, wf3, D3, N3PAD, D2);
}

// x (8192x480 fp32) -> xp (8192x512 fp16, zero-padded)
__global__ void pad_x(const float* __restrict__ x, u16* __restrict__ xp) {
    int total = BATCH * 128;
    for (int idx = blockIdx.x * blockDim.x + threadIdx.x; idx < total;
         idx += gridDim.x * blockDim.x) {
        int b = idx >> 7, k4 = idx & 127;
        ushort4 w;
        if (k4 < 120) {
            const float4 v = *reinterpret_cast<const float4*>(
                x + (size_t)b * D0 + (k4 << 2));
            w.x = f2h(v.x); w.y = f2h(v.y); w.z = f2h(v.z); w.w = f2h(v.w);
        } else {
            w.x = 0; w.y = 0; w.z = 0; w.w = 0;
        }
        *reinterpret_cast<ushort4*>(xp + (size_t)b * KP + (k4 << 2)) = w;
    }
}

// Per-expert GEMM: P[e][m][n] (fp16) = (A @ Bw[e]^T)[m,n]
// Tile 256x128, BK=64, nk=8; 512 threads = 8 waves (2m x 4n), wave-tile 128x32.
// Grid = 32(bm) * nbn * 8(e), XCD-swizzled on bm.
__global__ __launch_bounds__(512, 4) void gemm_e(
    const u16* __restrict__ A, const u16* __restrict__ Bw,
    u16* __restrict__ P, int OUTP, int nbn) {
    __shared__ __align__(16) u16 S[24576];  // 48 KB: As 16384 elems, Bs 8192 elems
    u16* As = S;
    u16* Bs = S + 16384;
    const int tid = threadIdx.x;
    const int w = tid >> 6, lane = tid & 63;
    const int wm = w & 1, wn = w >> 1;
    const int q = lane >> 4, l15 = lane & 15;

    const int id = blockIdx.x;
    const int xcd = id & 7;
    const int j = id >> 3;
    const int bm = ((j & 3) << 3) + xcd;   // 32 m-tiles; same bm -> same XCD
    const int rest = j >> 2;
    const int bn = rest % nbn;
    const int e = rest / nbn;

    f32x4 acc[8][2];
#pragma unroll
    for (int mi = 0; mi < 8; ++mi)
#pragma unroll
        for (int ni = 0; ni < 2; ++ni) acc[mi][ni] = (f32x4){0.f, 0.f, 0.f, 0.f};

    // staging: wave w -> A rows [w*32, w*32+32), B rows [w*16, w*16+16)
    const int l8 = lane & 7, h8 = lane >> 3;
    const int c8 = (l8 ^ h8) << 3;  // XOR-swizzled k source offset
    const u16* gA = A + (size_t)(bm * 256 + w * 32 + h8) * KP + c8;
    const u16* gB = Bw + ((size_t)e * OUTP + bn * 128 + w * 16 + h8) * KP + c8;
    u16* sA0 = As + w * 2048;
    u16* sB0 = Bs + w * 1024;

    for (int kt = 0; kt < 8; ++kt) {
        async16(gA, sA0);
        async16(gA + 4096, sA0 + 512);
        async16(gA + 8192, sA0 + 1024);
        async16(gA + 12288, sA0 + 1536);
        async16(gB, sB0);
        async16(gB + 4096, sB0 + 512);
        gA += 64; gB += 64;
        __syncthreads();
#pragma unroll
        for (int ks = 0; ks < 2; ++ks) {
            const int cs = (((q ^ (l15 & 7)) << 3) ^ (ks << 5));
            f16x8 af[8], bf[2];
#pragma unroll
            for (int mi = 0; mi < 8; ++mi)
                af[mi] = *reinterpret_cast<const f16x8*>(
                    &As[(wm * 128 + mi * 16 + l15) * 64 + cs]);
#pragma unroll
            for (int ni = 0; ni < 2; ++ni)
                bf[ni] = *reinterpret_cast<const f16x8*>(
                    &Bs[(wn * 32 + ni * 16 + l15) * 64 + cs]);
#pragma unroll
            for (int mi = 0; mi < 8; ++mi)
#pragma unroll
                for (int ni = 0; ni < 2; ++ni)
                    acc[mi][ni] = __builtin_amdgcn_mfma_f32_16x16x32_f16(
                        af[mi], bf[ni], acc[mi][ni], 0, 0, 0);
        }
        __syncthreads();
    }

    // epilogue: LDS transpose (128x136 u16) per 128-row half -> coalesced dwordx4
    u16* T = S;
#pragma unroll
    for (int hf = 0; hf < 2; ++hf) {
        if (hf == 1) __syncthreads();
        if (wm == hf) {
#pragma unroll
            for (int mi = 0; mi < 8; ++mi)
#pragma unroll
                for (int ni = 0; ni < 2; ++ni)
#pragma unroll
                    for (int r = 0; r < 4; ++r)
                        T[(mi * 16 + q * 4 + r) * 136 + wn * 32 + ni * 16 + l15] =
                            f2h(acc[mi][ni][r]);
        }
        __syncthreads();
        {
            const int row = tid >> 2, ch = tid & 3;
            const u16* src = T + row * 136 + ch * 32;
            u16* dst = P + ((size_t)e * BATCH + bm * 256 + hf * 128 + row) * OUTP +
                       bn * 128 + ch * 32;
#pragma unroll
            for (int u = 0; u < 4; ++u)
                *reinterpret_cast<int4*>(dst + u * 8) =
                    *reinterpret_cast<const int4*>(src + u * 8);
        }
    }
}

// h[b,n] = elu( sum_e bl[e,b]*P[e][b][n] + sum_e bl[e,b]*bias[e][n] ), fp16 out.
// One wave per row (64 lanes x 8 cols = 512); 4 rows per block.
__global__ __launch_bounds__(256) void reduce_blend(
    const u16* __restrict__ P, const float* __restrict__ blend,
    const float* __restrict__ bias, u16* __restrict__ h) {
    const int w = threadIdx.x >> 6, lane = threadIdx.x & 63;
    const int b = blockIdx.x * 4 + w;
    const int o0 = lane << 3;
    float bl[E_EXP];
#pragma unroll
    for (int e = 0; e < E_EXP; ++e) bl[e] = blend[e * BATCH + b];
    float v[8];
#pragma unroll
    for (int jj = 0; jj < 8; ++jj) v[jj] = 0.f;
#pragma unroll
    for (int e = 0; e < E_EXP; ++e) {
        const f16x8 p = *reinterpret_cast<const f16x8*>(
            P + ((size_t)e * BATCH + b) * 512 + o0);
        float s = bl[e];
#pragma unroll
        for (int jj = 0; jj < 8; ++jj) v[jj] += s * (float)p[jj];
    }
#pragma unroll
    for (int e = 0; e < E_EXP; ++e) {
        const float* bp = bias + e * 512 + o0;
        float4 a = *reinterpret_cast<const float4*>(bp);
        float4 c = *reinterpret_cast<const float4*>(bp + 4);
        float s = bl[e];
        v[0] += s * a.x; v[1] += s * a.y; v[2] += s * a.z; v[3] += s * a.w;
        v[4] += s * c.x; v[5] += s * c.y; v[6] += s * c.z; v[7] += s * c.w;
    }
    u16x8 o;
#pragma unroll
    for (int jj = 0; jj < 8; ++jj) {
        float t = v[jj] > 0.f ? v[jj] : expm1f(v[jj]);
        o[jj] = f2h(t);
    }
    *reinterpret_cast<u16x8*>(h + (size_t)b * 512 + o0) = o;
}

// logits = sum_e bl*P3 + sum_e bl*b3; softmax over 363 -> fp32 out.
__global__ __launch_bounds__(128) void reduce_softmax(
    const u16* __restrict__ P, const float* __restrict__ blend,
    const float* __restrict__ bias, float* __restrict__ out) {
    const int b = blockIdx.x;
    const int tid = threadIdx.x, lane = tid & 63, w = tid >> 6;
    float bl[E_EXP];
#pragma unroll
    for (int e = 0; e < E_EXP; ++e) bl[e] = blend[e * BATCH + b];
    float v[3];
    int n = 0;
    float mx = -3.4e38f;
    for (int i = tid; i < D3; i += 128) {
        float s = 0.f;
#pragma unroll
        for (int e = 0; e < E_EXP; ++e)
            s += bl[e] * (float)*reinterpret_cast<const _Float16*>(
                P + ((size_t)e * BATCH + b) * N3PAD + i);
#pragma unroll
        for (int e = 0; e < E_EXP; ++e) s += bl[e] * bias[e * D3 + i];
        v[n] = s; mx = fmaxf(mx, s); ++n;
    }
#pragma unroll
    for (int off = 32; off >= 1; off >>= 1) mx = fmaxf(mx, __shfl_xor(mx, off, 64));
    __shared__ float sm[4];
    if (lane == 0) sm[w] = mx;
    __syncthreads();
    mx = fmaxf(sm[0], sm[1]);
    float s = 0.f;
    for (int jj = 0; jj < n; ++jj) { v[jj] = expf(v[jj] - mx); s += v[jj]; }
#pragma unroll
    for (int off = 32; off >= 1; off >>= 1) s += __shfl_xor(s, off, 64);
    if (lane == 0) sm[2 + w] = s;
    __syncthreads();
    float inv = 1.f / (sm[2] + sm[3]);
    n = 0;
    for (int i = tid; i < D3; i += 128) { out[(size_t)b * D3 + i] = v[n] * inv; ++n; }
}

extern "C" void kernel_launch(void* const* d_in, const int* in_sizes, int n_in,
                              void* d_out, int out_size, void* d_ws, size_t ws_size,
                              hipStream_t stream) {
    const float* x = (const float*)d_in[0];
    const float* blend = (const float*)d_in[1];
    const float* W1 = (const float*)d_in[2];
    const float* b1 = (const float*)d_in[3];
    const float* W2 = (const float*)d_in[4];
    const float* b2 = (const float*)d_in[5];
    const float* W3 = (const float*)d_in[6];
    const float* b3 = (const float*)d_in[7];
    float* outp = (float*)d_out;

    char* ws = (char*)d_ws;
    u16* wf1 = (u16*)ws; ws += (size_t)E_EXP * 512 * KP * 2;    // 4.19 MB
    u16* wf2 = (u16*)ws; ws += (size_t)E_EXP * 512 * KP * 2;    // 4.19 MB
    u16* wf3 = (u16*)ws; ws += (size_t)E_EXP * N3PAD * KP * 2;  // 3.15 MB
    u16* xp = (u16*)ws;  ws += (size_t)BATCH * KP * 2;          // 8.39 MB
    u16* h1 = (u16*)ws;  ws += (size_t)BATCH * KP * 2;          // 8.39 MB
    u16* h2 = (u16*)ws;  ws += (size_t)BATCH * KP * 2;          // 8.39 MB
    u16* P = (u16*)ws;                                          // 8*8192*512*2 = 67.1 MB

    pack_all<<<1024, 256, 0, stream>>>(W1, W2, W3, wf1, wf2, wf3);
    pad_x<<<2048, 256, 0, stream>>>(x, xp);

    gemm_e<<<32 * 4 * E_EXP, 512, 0, stream>>>(xp, wf1, P, 512, 4);
    reduce_blend<<<BATCH / 4, 256, 0, stream>>>(P, blend, b1, h1);
    gemm_e<<<32 * 4 * E_EXP, 512, 0, stream>>>(h1, wf2, P, 512, 4);
    reduce_blend<<<BATCH / 4, 256, 0, stream>>>(P, blend, b2, h2);
    gemm_e<<<32 * 3 * E_EXP, 512, 0, stream>>>(h2, wf3, P, N3PAD, 3);
    reduce_softmax<<<BATCH, 128, 0, stream>>>(P, blend, b3, outp);
}